// Round 14
// baseline (117.693 us; speedup 1.0000x reference)
//
#include <hip/hip_runtime.h>
#include <hip/hip_fp16.h>

constexpr int R = 1024;
constexpr int C = 4096;
constexpr int N_CELLS = 8192;

constexpr unsigned LMAXT   = 32u;            // per-col list capacity
constexpr unsigned SLOT    = 44u;            // e3 words per lane per window
constexpr unsigned WSTRIDE = SLOT * 64u;     // 2816
constexpr unsigned SENT    = 4096u;          // zero-sentinel LDS index
constexpr unsigned PAD_ENTRY = SENT | (SENT << 13);

// Workspace (u32 indices)
constexpr size_t WS_CURSOR = 0;              // 4096 per-col counts
constexpr size_t WS_DONE   = 4096;           // last-block-done counter (pad to 4112)
constexpr size_t WS_META   = 4112;           // 64 per-window pair-trip counts
constexpr size_t WS_SORTED = 4176;           // 4096 col-of-rank
constexpr size_t WS_TMP    = 8272;           // 4096*32 per-col entry lists
constexpr size_t WS_E3     = 139344;         // 64*2816 padded interleaved lists

__device__ inline __half2 h2(unsigned u) { return *reinterpret_cast<__half2*>(&u); }

__device__ inline uint2 packh4(float v0, float v1, float v2, float v3) {
    __half2 h01 = __float22half2_rn(make_float2(v0, v1));
    __half2 h23 = __float22half2_rn(make_float2(v2, v3));
    uint2 u;
    u.x = *reinterpret_cast<unsigned*>(&h01);
    u.y = *reinterpret_cast<unsigned*>(&h23);
    return u;
}

// ---- prep (fused): fill per-col lists; last block counting-sorts columns by
// count (desc), emits sortedcol/meta, and reorders lists into padded
// pair-interleaved e3 slots by rank. Entry word: oa | ob<<13. ----
__global__ __launch_bounds__(256) void fill_sort_kernel(
    const int* __restrict__ i0, const int* __restrict__ i1,
    const int* __restrict__ i2, unsigned* __restrict__ cursor,
    unsigned* __restrict__ done, unsigned* __restrict__ meta,
    unsigned* __restrict__ sortedcol, unsigned* __restrict__ tmp,
    unsigned* __restrict__ e3)
{
    const int n = blockIdx.x * 256 + threadIdx.x;
    if (n < N_CELLS) {
        const unsigned a = (unsigned)i0[n], b = (unsigned)i1[n], c = (unsigned)i2[n];
        auto put = [&](unsigned col, unsigned oa, unsigned ob) {
            const unsigned i = atomicAdd(&cursor[col], 1u);
            if (i < LMAXT) tmp[col * LMAXT + i] = oa | (ob << 13);
        };
        put(a, b, c);
        put(b, a, c);
        put(c, a, b);
    }

    __syncthreads();
    __threadfence();
    __shared__ unsigned isLast;
    if (threadIdx.x == 0)
        isLast = (atomicAdd(done, 1u) + 1u == gridDim.x) ? 1u : 0u;
    __syncthreads();
    if (!isLast) return;
    __threadfence();   // acquire all blocks' cursor/tmp writes

    // ---- counting sort (desc) of 4096 columns by count ----
    __shared__ unsigned hist[33];
    __shared__ unsigned binbase[33];
    __shared__ unsigned cnt_lds[C];
    __shared__ unsigned sorted_lds[C];
    const int t = threadIdx.x;
    if (t < 33) hist[t] = 0;
    __syncthreads();

    unsigned cnt[16];
    #pragma unroll
    for (int j = 0; j < 16; ++j) {
        const int c = t * 16 + j;
        unsigned v = cursor[c];
        if (v > LMAXT) v = LMAXT;
        cnt[j] = v;
        cnt_lds[c] = v;
        atomicAdd(&hist[v], 1u);
    }
    __syncthreads();
    if (t == 0) {
        unsigned acc = 0;
        for (int v = 32; v >= 0; --v) { binbase[v] = acc; acc += hist[v]; }
    }
    __syncthreads();
    #pragma unroll
    for (int j = 0; j < 16; ++j) {
        const int c = t * 16 + j;
        const unsigned rank = atomicAdd(&binbase[cnt[j]], 1u);
        sorted_lds[rank] = (unsigned)c;
    }
    __syncthreads();

    // ---- reorder + pad; meta ----
    #pragma unroll
    for (int j = 0; j < 16; ++j) {
        const unsigned rk = (unsigned)t * 16u + (unsigned)j;
        const unsigned col = sorted_lds[rk];
        const unsigned cn  = cnt_lds[col];
        const unsigned w = rk >> 6, lane = rk & 63u;
        const unsigned m = cnt_lds[sorted_lds[w * 64u]];   // window max (desc)
        const unsigned npairs = (m + 1u) >> 1;
        if (lane == 0) meta[w] = npairs;
        sortedcol[rk] = col;
        const unsigned P2 = npairs * 2u + 4u;              // incl. pipeline cushion
        const unsigned base = w * WSTRIDE + lane * 2u;
        unsigned i = 0;
        for (; i < cn; ++i)
            e3[base + (i >> 1) * 128u + (i & 1u)] = tmp[col * LMAXT + i];
        for (; i < P2; ++i)
            e3[base + (i >> 1) * 128u + (i & 1u)] = PAD_ENTRY;
    }
}

// ---- main: one block per r, 512 threads, 32 KiB+8 LDS -> 4 blocks/CU.
// Gather sorted windows (short trips), then permute p1 back to natural column
// order through the SAME LDS buffer (rows are dead after own-save), then
// coalesced NT stores. R8 execution shape preserved.
__global__ __launch_bounds__(512, 8) void gather_kernel(
    const float* __restrict__ in,
    const unsigned* __restrict__ meta,
    const unsigned* __restrict__ sortedcol,
    const unsigned* __restrict__ e3,
    float* __restrict__ out)
{
    __shared__ uint2 sh[C + 1];   // 32776 B; sh[4096] = zero sentinel

    const int r = blockIdx.x;
    const int t = threadIdx.x;

    const float* __restrict__ p0r = in + ((size_t)0 * R + r) * C;
    const float* __restrict__ p1r = in + ((size_t)1 * R + r) * C;
    const float* __restrict__ p2r = in + ((size_t)2 * R + r) * C;
    const float* __restrict__ p3r = in + ((size_t)3 * R + r) * C;

    #pragma unroll
    for (int j = 0; j < 2; ++j) {
        const int c = t * 8 + j * 4;
        const float4 a = *reinterpret_cast<const float4*>(p0r + c);
        const float4 b = *reinterpret_cast<const float4*>(p1r + c);
        const float4 d = *reinterpret_cast<const float4*>(p2r + c);
        const float4 g = *reinterpret_cast<const float4*>(p3r + c);
        sh[c + 0] = packh4(a.x, b.x, d.x, g.x);
        sh[c + 1] = packh4(a.y, b.y, d.y, g.y);
        sh[c + 2] = packh4(a.z, b.z, d.z, g.z);
        sh[c + 3] = packh4(a.w, b.w, d.w, g.w);
    }
    if (t == 0) sh[SENT] = make_uint2(0u, 0u);
    __syncthreads();

    const unsigned wave = (unsigned)t >> 6;
    const unsigned lane = (unsigned)t & 63u;

    unsigned mycol[8];
    uint2 res[8];
    uint2 ownv[8];

    // ---- gather sorted windows (strided over waves for balance) ----
    #pragma unroll
    for (int k = 0; k < 8; ++k) {
        const unsigned w = wave + 8u * (unsigned)k;
        const unsigned npairs = meta[w];
        mycol[k] = sortedcol[w * 64u + lane];
        const uint2* __restrict__ lst2 =
            reinterpret_cast<const uint2*>(e3 + w * WSTRIDE) + lane;

        __half2 accA01 = __float2half2_rn(0.f), accA23 = accA01;
        __half2 accB01 = accA01, accB23 = accA01;

        uint2 pc = lst2[0];
        uint2 pn = lst2[64];
        uint2 A0 = sh[pc.x & 8191u], B0 = sh[pc.x >> 13];
        uint2 A1 = sh[pc.y & 8191u], B1 = sh[pc.y >> 13];

        for (unsigned j = 0; j < npairs; ++j) {
            const uint2 p2w = lst2[(j + 2) * 64u];
            const uint2 A0n = sh[pn.x & 8191u], B0n = sh[pn.x >> 13];
            const uint2 A1n = sh[pn.y & 8191u], B1n = sh[pn.y >> 13];

            accA01 = __hfma2(h2(A0.x), h2(B0.x), accA01);
            accA23 = __hfma2(h2(A0.y), h2(B0.y), accA23);
            accB01 = __hfma2(h2(A1.x), h2(B1.x), accB01);
            accB23 = __hfma2(h2(A1.y), h2(B1.y), accB23);

            pc = pn; pn = p2w;
            A0 = A0n; B0 = B0n; A1 = A1n; B1 = B1n;
        }

        const __half2 s01 = __hadd2(accA01, accB01);
        const __half2 s23 = __hadd2(accA23, accB23);
        uint2 rv;
        rv.x = *reinterpret_cast<const unsigned*>(&s01);
        rv.y = *reinterpret_cast<const unsigned*>(&s23);
        res[k] = rv;
    }

    // ---- save own values for the STORE columns before rows are overwritten ----
    #pragma unroll
    for (int k = 0; k < 8; ++k)
        ownv[k] = sh[(wave * 8u + (unsigned)k) * 64u + lane];
    __syncthreads();   // all rows reads complete

    // ---- permute p1 into natural column order (reuse rows buffer) ----
    #pragma unroll
    for (int k = 0; k < 8; ++k)
        sh[mycol[k]] = res[k];
    __syncthreads();

    // ---- coalesced NT stores ----
    #pragma unroll
    for (int k = 0; k < 8; ++k) {
        const unsigned c = (wave * 8u + (unsigned)k) * 64u + lane;
        const uint2 pr = sh[c];
        const float2 f01 = __half22float2(h2(pr.x));
        const float2 f23 = __half22float2(h2(pr.y));
        const float2 o01 = __half22float2(h2(ownv[k].x));
        const float2 o23 = __half22float2(h2(ownv[k].y));

        __builtin_nontemporal_store(o01.x * f01.x, out + ((size_t)0 * R + r) * C + c);
        __builtin_nontemporal_store(o01.y * f01.y, out + ((size_t)1 * R + r) * C + c);
        __builtin_nontemporal_store(o23.x * f23.x, out + ((size_t)2 * R + r) * C + c);
        __builtin_nontemporal_store(o23.y * f23.y, out + ((size_t)3 * R + r) * C + c);
        __builtin_nontemporal_store(f01.x,         out + ((size_t)4 * R + r) * C + c);
        __builtin_nontemporal_store(f01.y,         out + ((size_t)5 * R + r) * C + c);
        __builtin_nontemporal_store(f23.x,         out + ((size_t)6 * R + r) * C + c);
        __builtin_nontemporal_store(f23.y,         out + ((size_t)7 * R + r) * C + c);
    }
}

extern "C" void kernel_launch(void* const* d_in, const int* in_sizes, int n_in,
                              void* d_out, int out_size, void* d_ws, size_t ws_size,
                              hipStream_t stream) {
    const float* in   = (const float*)d_in[0];
    const int*   idx0 = (const int*)d_in[1];
    const int*   idx1 = (const int*)d_in[2];
    const int*   idx2 = (const int*)d_in[3];
    float* out = (float*)d_out;

    unsigned* ws        = (unsigned*)d_ws;
    unsigned* cursor    = ws + WS_CURSOR;
    unsigned* done      = ws + WS_DONE;
    unsigned* meta      = ws + WS_META;
    unsigned* sortedcol = ws + WS_SORTED;
    unsigned* tmp       = ws + WS_TMP;
    unsigned* e3        = ws + WS_E3;

    // zero cursor + done (contiguous prefix)
    hipMemsetAsync(ws, 0, 4112 * sizeof(unsigned), stream);

    fill_sort_kernel<<<dim3(N_CELLS / 256), dim3(256), 0, stream>>>(
        idx0, idx1, idx2, cursor, done, meta, sortedcol, tmp, e3);
    gather_kernel<<<dim3(R), dim3(512), 0, stream>>>(in, meta, sortedcol, e3, out);
}

// Round 15
// 65.050 us; speedup vs baseline: 1.8093x; 1.8093x over previous
//
#include <hip/hip_runtime.h>
#include <hip/hip_fp16.h>

constexpr int R = 1024;
constexpr int C = 4096;
constexpr int N_CELLS = 8192;

constexpr unsigned LMAXT   = 32u;            // per-col list capacity
constexpr unsigned SLOT    = 44u;            // e3 words per lane per window
constexpr unsigned WSTRIDE = SLOT * 64u;     // 2816
constexpr unsigned SENT    = 4096u;          // zero-sentinel LDS index
constexpr unsigned PAD_ENTRY = SENT | (SENT << 13);

// Workspace (u32 indices)
constexpr size_t WS_CURSOR = 0;              // 4096 per-col counts
constexpr size_t WS_META   = 4112;           // 64 per-window pair-trip counts
constexpr size_t WS_SORTED = 4176;           // 4096 col-of-rank
constexpr size_t WS_TMP    = 8272;           // 4096*32 per-col entry lists
constexpr size_t WS_E3     = 139344;         // 64*2816 padded interleaved lists

__device__ inline __half2 h2(unsigned u) { return *reinterpret_cast<__half2*>(&u); }

__device__ inline uint2 packh4(float v0, float v1, float v2, float v3) {
    __half2 h01 = __float22half2_rn(make_float2(v0, v1));
    __half2 h23 = __float22half2_rn(make_float2(v2, v3));
    uint2 u;
    u.x = *reinterpret_cast<unsigned*>(&h01);
    u.y = *reinterpret_cast<unsigned*>(&h23);
    return u;
}

// ---- prep 1: per-column entry lists (fixed stride), counts in cursor ----
__global__ void fill_kernel(const int* __restrict__ i0, const int* __restrict__ i1,
                            const int* __restrict__ i2, unsigned* __restrict__ cursor,
                            unsigned* __restrict__ tmp) {
    const int n = blockIdx.x * 256 + threadIdx.x;
    if (n < N_CELLS) {
        const unsigned a = (unsigned)i0[n], b = (unsigned)i1[n], c = (unsigned)i2[n];
        auto put = [&](unsigned col, unsigned oa, unsigned ob) {
            const unsigned i = atomicAdd(&cursor[col], 1u);
            if (i < LMAXT) tmp[col * LMAXT + i] = oa | (ob << 13);
        };
        put(a, b, c);
        put(b, a, c);
        put(c, a, b);
    }
}

// ---- prep 2: counting-sort columns by count (descending), one block ----
__global__ __launch_bounds__(1024) void sortbuild_kernel(
    const unsigned* __restrict__ cursor,
    unsigned* __restrict__ sortedcol,   // [4096] col of rank
    unsigned* __restrict__ meta)        // [64] pair-trips per window
{
    __shared__ unsigned hist[33];
    __shared__ unsigned binbase[33];
    __shared__ unsigned cnt_lds[C];
    __shared__ unsigned sorted_lds[C];
    const int t = threadIdx.x;
    if (t < 33) hist[t] = 0;
    __syncthreads();

    unsigned cnt[4];
    #pragma unroll
    for (int j = 0; j < 4; ++j) {
        const int c = t + 1024 * j;
        unsigned v = cursor[c];
        if (v > LMAXT) v = LMAXT;
        cnt[j] = v;
        cnt_lds[c] = v;
        atomicAdd(&hist[v], 1u);
    }
    __syncthreads();
    if (t == 0) {
        unsigned acc = 0;
        for (int v = 32; v >= 0; --v) { binbase[v] = acc; acc += hist[v]; }
    }
    __syncthreads();
    #pragma unroll
    for (int j = 0; j < 4; ++j) {
        const int c = t + 1024 * j;
        const unsigned rank = atomicAdd(&binbase[cnt[j]], 1u);
        sorted_lds[rank] = (unsigned)c;
    }
    __syncthreads();
    #pragma unroll
    for (int j = 0; j < 4; ++j) {
        const int rk = t + 1024 * j;
        sortedcol[rk] = sorted_lds[rk];
    }
    if (t < 64) {
        const unsigned m = cnt_lds[sorted_lds[64 * t]];   // window max (desc sort)
        meta[t] = (m + 1u) >> 1;                          // pair-iterations
    }
}

// ---- prep 3: parallel reorder into padded pair-interleaved e3 by rank ----
__global__ __launch_bounds__(256) void reorder_kernel(
    const unsigned* __restrict__ cursor,
    const unsigned* __restrict__ sortedcol,
    const unsigned* __restrict__ meta,
    const unsigned* __restrict__ tmp,
    unsigned* __restrict__ e3)
{
    const unsigned rank = blockIdx.x * 256u + threadIdx.x;
    const unsigned col  = sortedcol[rank];
    unsigned cnt = cursor[col];
    if (cnt > LMAXT) cnt = LMAXT;
    const unsigned w = rank >> 6, lane = rank & 63u;
    const unsigned P2 = meta[w] * 2u + 4u;                // incl. pipeline cushion
    const unsigned base = w * WSTRIDE + lane * 2u;
    unsigned i = 0;
    for (; i < cnt; ++i)
        e3[base + (i >> 1) * 128u + (i & 1u)] = tmp[col * LMAXT + i];
    for (; i < P2; ++i)
        e3[base + (i >> 1) * 128u + (i & 1u)] = PAD_ENTRY;
}

// ---- main (R13's gather, unchanged): one block per r, 512 threads,
// 32 KiB+8 LDS -> 4 blocks/CU. Gather sorted windows (short trips), permute
// p1 to natural order through the same LDS buffer, coalesced NT stores. ----
__global__ __launch_bounds__(512, 8) void gather_kernel(
    const float* __restrict__ in,
    const unsigned* __restrict__ meta,
    const unsigned* __restrict__ sortedcol,
    const unsigned* __restrict__ e3,
    float* __restrict__ out)
{
    __shared__ uint2 sh[C + 1];   // 32776 B; sh[4096] = zero sentinel

    const int r = blockIdx.x;
    const int t = threadIdx.x;

    const float* __restrict__ p0r = in + ((size_t)0 * R + r) * C;
    const float* __restrict__ p1r = in + ((size_t)1 * R + r) * C;
    const float* __restrict__ p2r = in + ((size_t)2 * R + r) * C;
    const float* __restrict__ p3r = in + ((size_t)3 * R + r) * C;

    #pragma unroll
    for (int j = 0; j < 2; ++j) {
        const int c = t * 8 + j * 4;
        const float4 a = *reinterpret_cast<const float4*>(p0r + c);
        const float4 b = *reinterpret_cast<const float4*>(p1r + c);
        const float4 d = *reinterpret_cast<const float4*>(p2r + c);
        const float4 g = *reinterpret_cast<const float4*>(p3r + c);
        sh[c + 0] = packh4(a.x, b.x, d.x, g.x);
        sh[c + 1] = packh4(a.y, b.y, d.y, g.y);
        sh[c + 2] = packh4(a.z, b.z, d.z, g.z);
        sh[c + 3] = packh4(a.w, b.w, d.w, g.w);
    }
    if (t == 0) sh[SENT] = make_uint2(0u, 0u);
    __syncthreads();

    const unsigned wave = (unsigned)t >> 6;
    const unsigned lane = (unsigned)t & 63u;

    unsigned mycol[8];
    uint2 res[8];
    uint2 ownv[8];

    // ---- gather sorted windows (strided over waves for balance) ----
    #pragma unroll
    for (int k = 0; k < 8; ++k) {
        const unsigned w = wave + 8u * (unsigned)k;
        const unsigned npairs = meta[w];
        mycol[k] = sortedcol[w * 64u + lane];
        const uint2* __restrict__ lst2 =
            reinterpret_cast<const uint2*>(e3 + w * WSTRIDE) + lane;

        __half2 accA01 = __float2half2_rn(0.f), accA23 = accA01;
        __half2 accB01 = accA01, accB23 = accA01;

        uint2 pc = lst2[0];
        uint2 pn = lst2[64];
        uint2 A0 = sh[pc.x & 8191u], B0 = sh[pc.x >> 13];
        uint2 A1 = sh[pc.y & 8191u], B1 = sh[pc.y >> 13];

        for (unsigned j = 0; j < npairs; ++j) {
            const uint2 p2w = lst2[(j + 2) * 64u];
            const uint2 A0n = sh[pn.x & 8191u], B0n = sh[pn.x >> 13];
            const uint2 A1n = sh[pn.y & 8191u], B1n = sh[pn.y >> 13];

            accA01 = __hfma2(h2(A0.x), h2(B0.x), accA01);
            accA23 = __hfma2(h2(A0.y), h2(B0.y), accA23);
            accB01 = __hfma2(h2(A1.x), h2(B1.x), accB01);
            accB23 = __hfma2(h2(A1.y), h2(B1.y), accB23);

            pc = pn; pn = p2w;
            A0 = A0n; B0 = B0n; A1 = A1n; B1 = B1n;
        }

        const __half2 s01 = __hadd2(accA01, accB01);
        const __half2 s23 = __hadd2(accA23, accB23);
        uint2 rv;
        rv.x = *reinterpret_cast<const unsigned*>(&s01);
        rv.y = *reinterpret_cast<const unsigned*>(&s23);
        res[k] = rv;
    }

    // ---- save own values for the STORE columns before rows are overwritten ----
    #pragma unroll
    for (int k = 0; k < 8; ++k)
        ownv[k] = sh[(wave * 8u + (unsigned)k) * 64u + lane];
    __syncthreads();   // all rows reads complete

    // ---- permute p1 into natural column order (reuse rows buffer) ----
    #pragma unroll
    for (int k = 0; k < 8; ++k)
        sh[mycol[k]] = res[k];
    __syncthreads();

    // ---- coalesced NT stores ----
    #pragma unroll
    for (int k = 0; k < 8; ++k) {
        const unsigned c = (wave * 8u + (unsigned)k) * 64u + lane;
        const uint2 pr = sh[c];
        const float2 f01 = __half22float2(h2(pr.x));
        const float2 f23 = __half22float2(h2(pr.y));
        const float2 o01 = __half22float2(h2(ownv[k].x));
        const float2 o23 = __half22float2(h2(ownv[k].y));

        __builtin_nontemporal_store(o01.x * f01.x, out + ((size_t)0 * R + r) * C + c);
        __builtin_nontemporal_store(o01.y * f01.y, out + ((size_t)1 * R + r) * C + c);
        __builtin_nontemporal_store(o23.x * f23.x, out + ((size_t)2 * R + r) * C + c);
        __builtin_nontemporal_store(o23.y * f23.y, out + ((size_t)3 * R + r) * C + c);
        __builtin_nontemporal_store(f01.x,         out + ((size_t)4 * R + r) * C + c);
        __builtin_nontemporal_store(f01.y,         out + ((size_t)5 * R + r) * C + c);
        __builtin_nontemporal_store(f23.x,         out + ((size_t)6 * R + r) * C + c);
        __builtin_nontemporal_store(f23.y,         out + ((size_t)7 * R + r) * C + c);
    }
}

extern "C" void kernel_launch(void* const* d_in, const int* in_sizes, int n_in,
                              void* d_out, int out_size, void* d_ws, size_t ws_size,
                              hipStream_t stream) {
    const float* in   = (const float*)d_in[0];
    const int*   idx0 = (const int*)d_in[1];
    const int*   idx1 = (const int*)d_in[2];
    const int*   idx2 = (const int*)d_in[3];
    float* out = (float*)d_out;

    unsigned* ws        = (unsigned*)d_ws;
    unsigned* cursor    = ws + WS_CURSOR;
    unsigned* meta      = ws + WS_META;
    unsigned* sortedcol = ws + WS_SORTED;
    unsigned* tmp       = ws + WS_TMP;
    unsigned* e3        = ws + WS_E3;

    hipMemsetAsync(cursor, 0, C * sizeof(unsigned), stream);

    fill_kernel<<<dim3(N_CELLS / 256), dim3(256), 0, stream>>>(idx0, idx1, idx2, cursor, tmp);
    sortbuild_kernel<<<dim3(1), dim3(1024), 0, stream>>>(cursor, sortedcol, meta);
    reorder_kernel<<<dim3(C / 256), dim3(256), 0, stream>>>(cursor, sortedcol, meta, tmp, e3);
    gather_kernel<<<dim3(R), dim3(512), 0, stream>>>(in, meta, sortedcol, e3, out);
}